// Round 3
// baseline (257.199 us; speedup 1.0000x reference)
//
#include <hip/hip_runtime.h>
#include <hip/hip_bf16.h>
#include <math.h>

// Problem constants
constexpr int T_ = 512;
constexpr int B_ = 4;
constexpr int E_ = 1024;
constexpr int H_ = 16;
constexpr int NGRAM_ = 2;
constexpr int TGT_ = (1 + NGRAM_) * T_;   // 1536
constexpr int ROWS_ = TGT_ * B_;          // 6144

typedef __bf16 bf16_t;
typedef __bf16 bf16x8 __attribute__((ext_vector_type(8)));
typedef __bf16 bf16x4 __attribute__((ext_vector_type(4)));
typedef float f32x4 __attribute__((ext_vector_type(4)));

#define GLL(gaddr, laddr)                                                     \
  __builtin_amdgcn_global_load_lds(                                           \
      (const __attribute__((address_space(1))) void*)(gaddr),                 \
      (__attribute__((address_space(3))) void*)(laddr), 16, 0, 0)

#define BARX()  asm volatile("s_barrier" ::: "memory")
#define WVM8()  asm volatile("s_waitcnt vmcnt(8)" ::: "memory")
#define WVM4()  asm volatile("s_waitcnt vmcnt(4)" ::: "memory")
#define WVM0()  asm volatile("s_waitcnt vmcnt(0)" ::: "memory")
#define LGKM0() asm volatile("s_waitcnt lgkmcnt(0)" ::: "memory")

// ---------------------------------------------------------------------------
// prep: all fp32->bf16 conversions, one launch.
// ---------------------------------------------------------------------------
__global__ __launch_bounds__(256) void prep(
    const float* __restrict__ query, const float* __restrict__ ipw,
    const float* __restrict__ relw, const float* __restrict__ outw,
    bf16_t* __restrict__ qb, bf16_t* __restrict__ ipwb,
    bf16_t* __restrict__ relwb, bf16_t* __restrict__ outwb) {
  const int i = blockIdx.x * 256 + threadIdx.x;
  constexpr int N1 = ROWS_ * E_ / 4;
  constexpr int N2 = 3 * E_ * E_ / 4;
  constexpr int N3 = 512 * E_ / 4;
  constexpr int N4 = E_ * E_ / 4;
  const float4* src;
  bf16_t* dst;
  int j = i;
  if (i < N1) { src = (const float4*)query; dst = qb; }
  else if (i < N1 + N2) { src = (const float4*)ipw; dst = ipwb; j = i - N1; }
  else if (i < N1 + N2 + N3) { src = (const float4*)relw; dst = relwb; j = i - N1 - N2; }
  else if (i < N1 + N2 + N3 + N4) { src = (const float4*)outw; dst = outwb; j = i - N1 - N2 - N3; }
  else return;
  const float4 v = src[j];
  bf16x4 o;
  o[0] = (bf16_t)v.x; o[1] = (bf16_t)v.y;
  o[2] = (bf16_t)v.z; o[3] = (bf16_t)v.w;
  ((bf16x4*)dst)[j] = o;
}

// ---------------------------------------------------------------------------
// Combined projection GEMM — faithful m201-style 256x256 8-phase template.
// BM=BN=256, BK=64, 512 threads (8 waves 2x4; per-wave 128x64 = acc[8][4]).
// LDS: 2 slots x (A 256x64 + B 256x64) bf16 = 128 KB.
// Per K-tile t (slot s=t&1): 4 phases (mq,kh); each phase:
//   { ds_read frags (8 or 4) ; stage ONE half-tile (2 GLL) ;
//     s_barrier ; lgkmcnt(0) ; setprio(1) ; 16 MFMA ; setprio(0) ; s_barrier }
// Stage targets: p0 -> B23(t+1), p1 -> A1(t+1)  [into slot s^1]
//                p2 -> A0(t+2),  p3 -> B01(t+2) [into slot s]
// Each target region is read-complete (lgkm0 + barrier) before overwrite.
// Boundary: vmcnt(4) + barrier per K-tile (vmcnt(8) prologue, vmcnt(0) @ t=15).
// Grid 14 x 24 = 336 = 8*42, bijective XCD swizzle.
// Epilogue routing:  bn<1024 Q(bf16*0.125) | <2048 K | <3072 V (LDS-bounce
// transpose to vT) | else relv2 fp32.
// ---------------------------------------------------------------------------
__device__ __forceinline__ int sw256(int row, int col) {
  return row * 256 + ((((col >> 3) ^ (row & 31)) << 3) | (col & 7));
}

__global__ __launch_bounds__(512, 2) void bgemm_proj(
    const bf16_t* __restrict__ A, const bf16_t* __restrict__ W,
    const float* __restrict__ ipb, const float* __restrict__ relb,
    bf16_t* __restrict__ qkvb, float* __restrict__ relv2,
    bf16_t* __restrict__ vT) {
  // slot s: A at s*32768, B at s*32768+16384 (bf16 elements)
  __shared__ __align__(16) bf16_t smem[65536];   // 128 KB

  const int tid = threadIdx.x;
  const int wave = tid >> 6, lane = tid & 63;
  const int wr = wave >> 2, wc = wave & 3;        // 2 x 4 wave grid
  const int pid = blockIdx.y * 14 + blockIdx.x;   // 336 = 8 * 42
  const int lid = (pid & 7) * 42 + (pid >> 3);
  const int by = lid / 14;
  const int bx = lid - by * 14;
  const int bm = by * 256, bn = bx * 256;
  const int q = lane >> 4, ln = lane & 15;
  const int grow = tid >> 3;                      // 0..63
  const int gcol = ((tid & 7) ^ (grow & 7)) * 8;  // pre-swizzled global col
  const int co[2] = {((q) ^ (ln & 7)) * 8, ((4 + q) ^ (ln & 7)) * 8};

  f32x4 acc[8][4];
#pragma unroll
  for (int mi = 0; mi < 8; ++mi)
#pragma unroll
    for (int ni = 0; ni < 4; ++ni)
#pragma unroll
      for (int r = 0; r < 4; ++r) acc[mi][ni][r] = 0.f;

  // one 64-row GLL round of A / B of K-tile kt
  auto stA = [&](int kt, int row0) {
    bf16_t* dst = smem + (kt & 1) * 32768 + row0 * 64;
    GLL(&A[(size_t)(bm + row0 + grow) * 1024 + kt * 64 + gcol], &dst[tid * 8]);
  };
  auto stB = [&](int kt, int row0) {
    bf16_t* dst = smem + (kt & 1) * 32768 + 16384 + row0 * 64;
    GLL(&W[(size_t)(bn + row0 + grow) * 1024 + kt * 64 + gcol], &dst[tid * 8]);
  };

  // prologue: K-tiles 0 and 1 fully staged (16 GLL)
  stA(0, 0); stA(0, 128); stB(0, 0); stB(0, 64);
  stB(0, 128); stB(0, 192); stA(0, 64); stA(0, 192);
  stA(1, 0); stA(1, 128); stB(1, 0); stB(1, 64);
  stB(1, 128); stB(1, 192); stA(1, 64); stA(1, 192);
  WVM8();          // tile 0 (oldest 8) resident; tile 1 in flight
  BARX();

#pragma unroll 1
  for (int kt = 0; kt < 16; ++kt) {
    const bf16_t* As = smem + (kt & 1) * 32768;
    const bf16_t* Bs = As + 16384;
    if (kt) {
      if (kt == 15) { WVM0(); } else { WVM4(); }  // tile kt resident
      BARX();
    }
    bf16x8 b0[4], b1[4], a[4];

    // -------- phase 0: (mq0, kh0) --------
#pragma unroll
    for (int ni = 0; ni < 4; ++ni)
      b0[ni] = *(const bf16x8*)&Bs[(wc * 64 + ni * 16 + ln) * 64 + co[0]];
#pragma unroll
    for (int mi = 0; mi < 4; ++mi)
      a[mi] = *(const bf16x8*)&As[(wr * 128 + mi * 16 + ln) * 64 + co[0]];
    if (kt >= 1 && kt <= 14) { stB(kt + 1, 128); stB(kt + 1, 192); }
    BARX(); LGKM0();
    __builtin_amdgcn_s_setprio(1);
#pragma unroll
    for (int mi = 0; mi < 4; ++mi)
#pragma unroll
      for (int ni = 0; ni < 4; ++ni)
        acc[mi][ni] = __builtin_amdgcn_mfma_f32_16x16x32_bf16(
            a[mi], b0[ni], acc[mi][ni], 0, 0, 0);
    __builtin_amdgcn_s_setprio(0);
    BARX();

    // -------- phase 1: (mq0, kh1) --------
#pragma unroll
    for (int ni = 0; ni < 4; ++ni)
      b1[ni] = *(const bf16x8*)&Bs[(wc * 64 + ni * 16 + ln) * 64 + co[1]];
#pragma unroll
    for (int mi = 0; mi < 4; ++mi)
      a[mi] = *(const bf16x8*)&As[(wr * 128 + mi * 16 + ln) * 64 + co[1]];
    if (kt >= 1 && kt <= 14) { stA(kt + 1, 64); stA(kt + 1, 192); }
    BARX(); LGKM0();
    __builtin_amdgcn_s_setprio(1);
#pragma unroll
    for (int mi = 0; mi < 4; ++mi)
#pragma unroll
      for (int ni = 0; ni < 4; ++ni)
        acc[mi][ni] = __builtin_amdgcn_mfma_f32_16x16x32_bf16(
            a[mi], b1[ni], acc[mi][ni], 0, 0, 0);
    __builtin_amdgcn_s_setprio(0);
    BARX();

    // -------- phase 2: (mq1, kh0) --------
#pragma unroll
    for (int mi = 0; mi < 4; ++mi)
      a[mi] = *(const bf16x8*)&As[(wr * 128 + 64 + mi * 16 + ln) * 64 + co[0]];
    if (kt <= 13) { stA(kt + 2, 0); stA(kt + 2, 128); }
    BARX(); LGKM0();
    __builtin_amdgcn_s_setprio(1);
#pragma unroll
    for (int mi = 0; mi < 4; ++mi)
#pragma unroll
      for (int ni = 0; ni < 4; ++ni)
        acc[4 + mi][ni] = __builtin_amdgcn_mfma_f32_16x16x32_bf16(
            a[mi], b0[ni], acc[4 + mi][ni], 0, 0, 0);
    __builtin_amdgcn_s_setprio(0);
    BARX();

    // -------- phase 3: (mq1, kh1) --------
#pragma unroll
    for (int mi = 0; mi < 4; ++mi)
      a[mi] = *(const bf16x8*)&As[(wr * 128 + 64 + mi * 16 + ln) * 64 + co[1]];
    if (kt <= 13) { stB(kt + 2, 0); stB(kt + 2, 64); }
    BARX(); LGKM0();
    __builtin_amdgcn_s_setprio(1);
#pragma unroll
    for (int mi = 0; mi < 4; ++mi)
#pragma unroll
      for (int ni = 0; ni < 4; ++ni)
        acc[4 + mi][ni] = __builtin_amdgcn_mfma_f32_16x16x32_bf16(
            a[mi], b1[ni], acc[4 + mi][ni], 0, 0, 0);
    __builtin_amdgcn_s_setprio(0);
    BARX();
  }

  // ---------------- epilogue (per-block uniform routing) -------------------
  if (bn < 2048) {
    // Q (scaled) and K -> qkvb
    const float sc = (bn < 1024) ? 0.125f : 1.0f;
#pragma unroll
    for (int mi = 0; mi < 8; ++mi) {
#pragma unroll
      for (int ni = 0; ni < 4; ++ni) {
        const int col = bn + wc * 64 + ni * 16 + ln;
        const float bv = ipb[col];
#pragma unroll
        for (int r = 0; r < 4; ++r) {
          const int row = bm + wr * 128 + mi * 16 + q * 4 + r;
          qkvb[(size_t)row * 3072 + col] = (bf16_t)((acc[mi][ni][r] + bv) * sc);
        }
      }
    }
  } else if (bn < 3072) {
    // V: transpose via swizzled 256x256 LDS bounce, write vT[bh][d][token]
    __syncthreads();  // K-loop fully drained; reuse all 128 KB as bounce
#pragma unroll
    for (int mi = 0; mi < 8; ++mi) {
#pragma unroll
      for (int ni = 0; ni < 4; ++ni) {
        const int col_l = wc * 64 + ni * 16 + ln;
        const float bv = ipb[bn + col_l];
#pragma unroll
        for (int r = 0; r < 4; ++r) {
          const int row_l = wr * 128 + mi * 16 + q * 4 + r;
          smem[sw256(row_l, col_l)] = (bf16_t)(acc[mi][ni][r] + bv);
        }
      }
    }
    __syncthreads();
    const int h0 = (bn - 2048) >> 6;     // 4 heads per 256-col tile
    const int tb0 = bm >> 2;             // 64 tokens per 256-row tile
#pragma unroll
    for (int e = 0; e < 2; ++e) {
      const int task = e * 512 + tid;    // 1024 tasks: (b, col)
      const int b = task & 3;
      const int c = task >> 2;           // 0..255
      const int h = h0 + (c >> 6);
      const int d = c & 63;
      const size_t base = ((size_t)((b * 16 + h) * 64 + d)) * (size_t)TGT_ + tb0;
#pragma unroll
      for (int k = 0; k < 8; ++k) {
        bf16x8 v8;
#pragma unroll
        for (int i = 0; i < 8; ++i)
          v8[i] = smem[sw256((k * 8 + i) * 4 + b, c)];
        *(bf16x8*)&vT[base + k * 8] = v8;
      }
    }
  } else {
    const int cb = bn - 3072 + wc * 64;
    float4 rb4;
#pragma unroll
    for (int ni = 0; ni < 4; ++ni)
      ((float*)&rb4)[ni] = relb[cb + ni * 16 + ln];
    const int bkbase = cb >> 4;
#pragma unroll
    for (int mi = 0; mi < 8; ++mi) {
#pragma unroll
      for (int r = 0; r < 4; ++r) {
        const int row = bm + wr * 128 + mi * 16 + q * 4 + r;
        float4 v;
        v.x = acc[mi][0][r] + rb4.x;
        v.y = acc[mi][1][r] + rb4.y;
        v.z = acc[mi][2][r] + rb4.z;
        v.w = acc[mi][3][r] + rb4.w;
        *(float4*)&relv2[(size_t)row * 512 + ln * 32 + bkbase] = v;
      }
    }
  }
}

// ---------------------------------------------------------------------------
// Output projection GEMM (fp32 out). Unchanged + XCD swizzle.
// ---------------------------------------------------------------------------
__global__ __launch_bounds__(256, 4) void bgemm_out(
    const bf16_t* __restrict__ A, const bf16_t* __restrict__ W,
    const float* __restrict__ bias, float* __restrict__ C, int N) {
  __shared__ bf16_t As[128 * 64];
  __shared__ bf16_t Bs[128 * 64];

  const int tid = threadIdx.x;
  const int wave = tid >> 6, lane = tid & 63;
  const int wr = wave >> 1, wc = wave & 1;
  const int pid = blockIdx.y * 8 + blockIdx.x;
  const int lid = (pid & 7) * 48 + (pid >> 3);
  const int bm = (lid >> 3) * 128, bn = (lid & 7) * 128;
  const int q = lane >> 4, ln = lane & 15;
  const int grow = tid >> 3;
  const int gcol = ((tid & 7) ^ (grow & 7)) * 8;

  f32x4 acc[4][4];
#pragma unroll
  for (int mi = 0; mi < 4; ++mi)
#pragma unroll
    for (int ni = 0; ni < 4; ++ni)
#pragma unroll
      for (int r = 0; r < 4; ++r) acc[mi][ni][r] = 0.f;

  const int co[2] = {((q) ^ (ln & 7)) * 8, ((4 + q) ^ (ln & 7)) * 8};

  for (int k0 = 0; k0 < 1024; k0 += 64) {
    __syncthreads();
#pragma unroll
    for (int p = 0; p < 4; ++p) {
      GLL(&A[(size_t)(bm + p * 32 + grow) * 1024 + k0 + gcol], &As[p * 2048 + tid * 8]);
      GLL(&W[(size_t)(bn + p * 32 + grow) * 1024 + k0 + gcol], &Bs[p * 2048 + tid * 8]);
    }
    __syncthreads();
#pragma unroll
    for (int t = 0; t < 2; ++t) {
      bf16x8 af[4], bf[4];
#pragma unroll
      for (int mi = 0; mi < 4; ++mi)
        af[mi] = *(const bf16x8*)&As[(wr * 64 + mi * 16 + ln) * 64 + co[t]];
#pragma unroll
      for (int ni = 0; ni < 4; ++ni)
        bf[ni] = *(const bf16x8*)&Bs[(wc * 64 + ni * 16 + ln) * 64 + co[t]];
#pragma unroll
      for (int mi = 0; mi < 4; ++mi)
#pragma unroll
        for (int ni = 0; ni < 4; ++ni)
          acc[mi][ni] = __builtin_amdgcn_mfma_f32_16x16x32_bf16(
              af[mi], bf[ni], acc[mi][ni], 0, 0, 0);
    }
  }

#pragma unroll
  for (int mi = 0; mi < 4; ++mi) {
#pragma unroll
    for (int ni = 0; ni < 4; ++ni) {
      const int col = bn + wc * 64 + ni * 16 + ln;
      const float bv = bias[col];
#pragma unroll
      for (int r = 0; r < 4; ++r) {
        const int row = bm + wr * 64 + mi * 16 + q * 4 + r;
        C[(size_t)row * N + col] = acc[mi][ni][r] + bv;
      }
    }
  }
}

// ---------------------------------------------------------------------------
// MFMA flash attention (unchanged this round).
// ---------------------------------------------------------------------------
__device__ __forceinline__ int bucket_of(int n) {
  if (n < 16) return n;
  const float lf = __log2f((float)n);
  int b = (int)(16.0f + (lf - 4.0f) * 5.3333333f);
  return b > 31 ? 31 : b;
}

__global__ __launch_bounds__(256, 2) void flash_mfma(
    const bf16_t* __restrict__ qkvb, const bf16_t* __restrict__ vT,
    const float* __restrict__ relv2, bf16_t* __restrict__ attn) {
  __shared__ bf16_t Ks[2][64 * 64];
  __shared__ bf16_t Vts[2][64 * 64];
  __shared__ bf16_t Ps[4][16 * 64];
  __shared__ bf16_t biasS[3][64 * 33];

  const int qt = 7 - blockIdx.x, tq0 = qt * 64;
  const int bh = blockIdx.y, b = bh >> 4, h = bh & 15;
  const int tid = threadIdx.x;
  const int wave = tid >> 6, lane = tid & 63;
  const int q = lane >> 4, ln = lane & 15;
  const int m0 = wave * 16;
  const int grow = tid >> 3;
  const int gcol = ((tid & 7) ^ (grow & 7)) * 8;
  const int co[2] = {((q) ^ (ln & 7)) * 8, ((4 + q) ^ (ln & 7)) * 8};

#pragma unroll
  for (int z = 0; z < 3; ++z) {
#pragma unroll
    for (int u = 0; u < 2; ++u) {
      const int c = u * 256 + tid;
      const int row = c >> 3, j4 = (c & 7) * 4;
      const float4 v = *(const float4*)
          &relv2[((size_t)(z * T_ + tq0 + row) * B_ + b) * 512 + h * 32 + j4];
      biasS[z][row * 33 + j4 + 0] = (bf16_t)v.x;
      biasS[z][row * 33 + j4 + 1] = (bf16_t)v.y;
      biasS[z][row * 33 + j4 + 2] = (bf16_t)v.z;
      biasS[z][row * 33 + j4 + 3] = (bf16_t)v.w;
    }
  }

#pragma unroll
  for (int u = 0; u < 2; ++u) {
    const int sr = u * 32 + grow;
    GLL(&qkvb[((size_t)(0 * T_ + tq0 + sr) * B_ + b) * 3072 + h * 64 + gcol],
        &Ks[0][u * 2048 + tid * 8]);
    GLL(&qkvb[((size_t)(1 * T_ + tq0 + sr) * B_ + b) * 3072 + h * 64 + gcol],
        &Vts[0][u * 2048 + tid * 8]);
    GLL(&qkvb[((size_t)(2 * T_ + tq0 + sr) * B_ + b) * 3072 + h * 64 + gcol],
        &Ks[1][u * 2048 + tid * 8]);
  }
  __syncthreads();

  bf16x8 aq[3][2];
  aq[0][0] = *(const bf16x8*)&Ks[0][(m0 + ln) * 64 + co[0]];
  aq[0][1] = *(const bf16x8*)&Ks[0][(m0 + ln) * 64 + co[1]];
  aq[1][0] = *(const bf16x8*)&Vts[0][(m0 + ln) * 64 + co[0]];
  aq[1][1] = *(const bf16x8*)&Vts[0][(m0 + ln) * 64 + co[1]];
  aq[2][0] = *(const bf16x8*)&Ks[1][(m0 + ln) * 64 + co[0]];
  aq[2][1] = *(const bf16x8*)&Ks[1][(m0 + ln) * 64 + co[1]];

  float bv31[3][4], bv0[3][4];
#pragma unroll
  for (int z = 0; z < 3; ++z)
#pragma unroll
    for (int r = 0; r < 4; ++r) {
      const int rloc = m0 + q * 4 + r;
      bv31[z][r] = (float)biasS[z][rloc * 33 + 31];
      bv0[z][r] = (float)biasS[z][rloc * 33];
    }

  f32x4 Od[3][4];
  float lpart[3][4];
#pragma unroll
  for (int z = 0; z < 3; ++z)
#pragma unroll
    for (int r = 0; r < 4; ++r) {
      lpart[z][r] = 0.f;
#pragma unroll
      for (int tc = 0; tc < 4; ++tc) Od[z][tc][r] = 0.f;
    }

  const int ntiles = qt + 3;

  auto stage_tile = [&](int jj, int buf) {
    const int krb = (jj <= qt) ? jj * 64 : ((jj - qt) * T_ + tq0);
#pragma unroll
    for (int u = 0; u < 2; ++u) {
      const int sr = u * 32 + grow;
      GLL(&qkvb[((size_t)(krb + sr) * B_ + b) * 3072 + 1024 + h * 64 + gcol],
          &Ks[buf][u * 2048 + tid * 8]);
      GLL(&vT[((size_t)bh * 64 + sr) * (size_t)TGT_ + krb + gcol],
          &Vts[buf][u * 2048 + tid * 8]);
    }
  };

  __syncthreads();
  stage_tile(0, 0);
  __syncthreads();

  for (int jj = 0; jj < ntiles; ++jj) {
    const int cur = jj & 1;
    if (jj + 1 < ntiles) stage_tile(jj + 1, cur ^ 1);

    const int krb = (jj <= qt) ? jj * 64 : ((jj - qt) * T_ + tq0);

    bf16x8 kf[4][2], vf[4][2];
#pragma unroll
    for (int tc = 0; tc < 4; ++tc) {
      kf[tc][0] = *(const bf16x8*)&Ks[cur][(tc * 16 + ln) * 64 + co[0]];
      kf[tc][1] = *(const bf16x8*)&Ks[cur][(tc * 16 + ln) * 64 + co[1]];
      vf[tc][0] = *(const bf16x8*)&Vts[cur][(tc * 16 + ln) * 64 + co[0]];
      vf[tc][1] = *(const bf16x8*)&Vts[cur][(tc * 16 + ln) * 64 + co[1]];
    }

    if (jj <= qt) {
      const bool far = (jj <= qt - 3);
#pragma unroll
      for (int z = 0; z < 3; ++z) {
        f32x4 acc[4];
#pragma unroll
        for (int tc = 0; tc < 4; ++tc)
#pragma unroll
          for (int r = 0; r < 4; ++r) acc[tc][r] = 0.f;
#pragma unroll
        for (int tc = 0; tc < 4; ++tc) {
          acc[tc] = __builtin_amdgcn_mfma_f32_16x16x32_bf16(aq[z][0], kf[tc][0], acc[tc], 0, 0, 0);
          acc[tc] = __builtin_amdgcn_mfma_f32_16x16x32_bf16(aq[z][1], kf[tc][1], acc[tc], 0, 0, 0);
        }

        if (far) {
#pragma unroll
          for (int r = 0; r < 4; ++r) {
            const float bv = bv31[z][r];
#pragma unroll
            for (int tc = 0; tc < 4; ++tc) {
              const float p = __expf(acc[tc][r] + bv);
              lpart[z][r] += p;
              const int pc = (tc * 2 + (ln >> 3)) ^ ((q * 4 + r) & 7);
              Ps[wave][(q * 4 + r) * 64 + pc * 8 + (ln & 7)] = (bf16_t)p;
            }
          }
        } else {
#pragma unroll
          for (int r = 0; r < 4; ++r) {
            const int rloc = m0 + q * 4 + r;
            const int dbase = tq0 + rloc - krb;
#pragma unroll
            for (int tc = 0; tc < 4; ++tc) {
              const int sl = tc * 16 + ln;
              const int d = dbase - sl;
              const bool valid = (jj < qt) | (d >= 0);
              int n = d < 0 ? 0 : d;
              if (z > 0) n += 1;
              const float bv = (float)biasS[z][rloc * 33 + bucket_of(n)];
              const float p = valid ? __expf(acc[tc][r] + bv) : 0.f;
              lpart[z][r] += p;
              const int pc = (tc * 2 + (ln >> 3)) ^ ((q * 4 + r) & 7);
              Ps[wave][(q * 4 + r) * 64 + pc * 8 + (ln & 7)] = (bf16_t)p;
            }
          }
        }

        bf16x8 ap[2];
        ap[0] = *(const bf16x8*)&Ps[wave][ln * 64 + co[0]];
        ap[1] = *(const bf16x8*)&Ps[wave][ln * 64 + co[1]];
#pragma unroll
        for (int tc = 0; tc < 4; ++tc) {
          Od[z][tc] = __builtin_amdgcn_mfma_f32_16x16x32_bf16(ap[0], vf[tc][0], Od[z][tc], 0, 0, 0);
          Od[z][tc] = __builtin_amdgcn_mfma_f32_16x16x32_bf16(ap[1], vf[tc][1], Od[z][tc], 0, 0, 0);
        }
      }
    } else {
#pragma unroll
      for (int z = 1; z <= 2; ++z) {
        if (jj - qt == z) {
          f32x4 acc[4];
#pragma unroll
          for (int tc = 0; tc < 4; ++tc)
#pragma unroll
            for (int r = 0; r < 4; ++r) acc[tc][r] = 0.f;
#pragma unroll
          for (int tc = 0; tc < 4; ++tc) {
            acc[tc] = __builtin_amdgcn_mfma_f32_16x16x32_bf16(aq[z][0], kf[tc][0], acc[tc], 0, 0, 0);
            acc[tc] = __builtin_amdgcn_mfma_f32_16x16x32_bf16(aq[z][1], kf[tc][1], acc[tc], 0, 0, 0);
          }
#pragma unroll
          for (int r = 0; r < 4; ++r) {
            const int rloc = m0 + q * 4 + r;
            const float bv = bv0[z][r];
#pragma unroll
            for (int tc = 0; tc < 4; ++tc) {
              const int sl = tc * 16 + ln;
              const float p = (sl == rloc) ? __expf(acc[tc][r] + bv) : 0.f;
              lpart[z][r] += p;
              const int pc = (tc * 2 + (ln >> 3)) ^ ((q * 4 + r) & 7);
              Ps[wave][(q * 4 + r) * 64 + pc * 8 + (ln & 7)] = (bf16_t)p;
            }
          }
          bf16x8 ap[2];
          ap[0] = *(const bf16x8*)&Ps[wave][ln * 64 + co[0]];
          ap[1] = *(const bf16x8*)&Ps[wave][ln * 64 + co[1]];
#pragma unroll
          for (int tc = 0; tc < 4; ++tc) {
            Od[z][tc] = __builtin_amdgcn_mfma_f32_16x16x32_bf16(ap[0], vf[tc][0], Od[z][tc], 0, 0, 0);
            Od[z][tc] = __builtin_amdgcn_mfma_f32_16x16x32_bf16(ap[1], vf[tc][1], Od[z][tc], 0, 0, 0);
          }
        }
      }
    }
    __syncthreads();
  }

#pragma unroll
  for (int z = 0; z < 3; ++z) {
#pragma unroll
    for (int r = 0; r < 4; ++r) {
      float l = lpart[z][r];
      l += __shfl_xor(l, 1, 16);
      l += __shfl_xor(l, 2, 16);
      l += __shfl_xor(l, 4, 16);
      l += __shfl_xor(l, 8, 16);
      const float inv = 1.f / l;
      const size_t rowbase =
          ((size_t)(z * T_ + tq0 + m0 + q * 4 + r) * B_ + b) * (size_t)E_ + h * 64;
#pragma unroll
      for (int tc = 0; tc < 4; ++tc)
        attn[rowbase + tc * 16 + ln] = (bf16_t)(Od[z][tc][r] * inv);
    }
  }
}

// ---------------------------------------------------------------------------
extern "C" void kernel_launch(void* const* d_in, const int* in_sizes, int n_in,
                              void* d_out, int out_size, void* d_ws, size_t ws_size,
                              hipStream_t stream) {
  const float* query = (const float*)d_in[0];
  const float* ipw   = (const float*)d_in[1];
  const float* ipb   = (const float*)d_in[2];
  const float* relw  = (const float*)d_in[3];
  const float* relb  = (const float*)d_in[4];
  const float* outw  = (const float*)d_in[5];
  const float* outb  = (const float*)d_in[6];
  float* out = (float*)d_out;

  bf16_t* qkvb  = (bf16_t*)d_ws;                                 // 6144x3072
  float*  relv2 = (float*)(qkvb + (size_t)ROWS_ * 3 * E_);       // 6144x512 f32
  bf16_t* qb    = (bf16_t*)(relv2 + (size_t)ROWS_ * 512);        // 6144x1024
  bf16_t* ipwb  = qb + (size_t)ROWS_ * E_;                       // 3072x1024
  bf16_t* relwb = ipwb + (size_t)(3 * E_) * E_;                  // 512x1024 (adjacent!)
  bf16_t* outwb = relwb + (size_t)512 * E_;                      // 1024x1024
  bf16_t* attnb = outwb + (size_t)E_ * E_;                       // 6144x1024
  bf16_t* vT    = attnb + (size_t)ROWS_ * E_;                    // 64x64x1536

  const dim3 blk(256);

  // 1) conversions
  {
    const int ntot = (ROWS_ * E_ + 3 * E_ * E_ + 512 * E_ + E_ * E_) / 4;
    prep<<<dim3((ntot + 255) / 256), blk, 0, stream>>>(
        query, ipw, relw, outw, qb, ipwb, relwb, outwb);
  }

  // 2) combined QKV + rel projection (256x256 8-phase template)
  bgemm_proj<<<dim3(3584 / 256, ROWS_ / 256), dim3(512), 0, stream>>>(
      qb, ipwb, ipb, relb, qkvb, relv2, vT);

  // 3) flash attention, all streams merged
  flash_mfma<<<dim3(8, B_ * H_), blk, 0, stream>>>(
      qkvb, vT, relv2, attnb);

  // 4) output projection
  bgemm_out<<<dim3(E_ / 128, ROWS_ / 128), blk, 0, stream>>>(
      attnb, outwb, outb, out, E_);
}

// Round 4
// 243.966 us; speedup vs baseline: 1.0542x; 1.0542x over previous
//
#include <hip/hip_runtime.h>
#include <hip/hip_bf16.h>
#include <math.h>

// Problem constants
constexpr int T_ = 512;
constexpr int B_ = 4;
constexpr int E_ = 1024;
constexpr int H_ = 16;
constexpr int NGRAM_ = 2;
constexpr int TGT_ = (1 + NGRAM_) * T_;   // 1536
constexpr int ROWS_ = TGT_ * B_;          // 6144

typedef __bf16 bf16_t;
typedef __bf16 bf16x8 __attribute__((ext_vector_type(8)));
typedef __bf16 bf16x4 __attribute__((ext_vector_type(4)));
typedef float f32x4 __attribute__((ext_vector_type(4)));

#define GLL(gaddr, laddr)                                                     \
  __builtin_amdgcn_global_load_lds(                                           \
      (const __attribute__((address_space(1))) void*)(gaddr),                 \
      (__attribute__((address_space(3))) void*)(laddr), 16, 0, 0)

#define BARX()  asm volatile("s_barrier" ::: "memory")
#define WVM7()  asm volatile("s_waitcnt vmcnt(7)" ::: "memory")
#define WVM4()  asm volatile("s_waitcnt vmcnt(4)" ::: "memory")
#define WVM0()  asm volatile("s_waitcnt vmcnt(0)" ::: "memory")
#define LGKM0() asm volatile("s_waitcnt lgkmcnt(0)" ::: "memory")

// ---------------------------------------------------------------------------
// prep: all fp32->bf16 conversions, one launch.
// ---------------------------------------------------------------------------
__global__ __launch_bounds__(256) void prep(
    const float* __restrict__ query, const float* __restrict__ ipw,
    const float* __restrict__ relw, const float* __restrict__ outw,
    bf16_t* __restrict__ qb, bf16_t* __restrict__ ipwb,
    bf16_t* __restrict__ relwb, bf16_t* __restrict__ outwb) {
  const int i = blockIdx.x * 256 + threadIdx.x;
  constexpr int N1 = ROWS_ * E_ / 4;
  constexpr int N2 = 3 * E_ * E_ / 4;
  constexpr int N3 = 512 * E_ / 4;
  constexpr int N4 = E_ * E_ / 4;
  const float4* src;
  bf16_t* dst;
  int j = i;
  if (i < N1) { src = (const float4*)query; dst = qb; }
  else if (i < N1 + N2) { src = (const float4*)ipw; dst = ipwb; j = i - N1; }
  else if (i < N1 + N2 + N3) { src = (const float4*)relw; dst = relwb; j = i - N1 - N2; }
  else if (i < N1 + N2 + N3 + N4) { src = (const float4*)outw; dst = outwb; j = i - N1 - N2 - N3; }
  else return;
  const float4 v = src[j];
  bf16x4 o;
  o[0] = (bf16_t)v.x; o[1] = (bf16_t)v.y;
  o[2] = (bf16_t)v.z; o[3] = (bf16_t)v.w;
  ((bf16x4*)dst)[j] = o;
}

// ---------------------------------------------------------------------------
// Combined projection GEMM: 8-phase-style schedule (r3, 47% per-block) on
// BM=192 x BN=256 geometry (r2 grid: 448 blocks = 2 rounds @ 87.5% packing).
// BK=64, 512 threads (8 waves 2x4). LDS 112 KB (2 slots x (A 192x64 + B
// 256x64)) -> 1 block/CU.
//
// Per K-tile: 3 phases, 16 MFMA each:
//  p0: read b0(4)+a_co0(4 frags, rows wr*128+j*16)   ; stage B(t+1) r128,r192
//  p1: read b1(4)+a_co1(4 frags, same rows)          ; stage A(t+1) r64
//  p2: read a2/a3 (2+2 frags, rows 64+32*wr+j*16)    ; stage A(t+2) r0,r128
//                                                      + B(t+2) r0,r64
//  each phase: {reads; stages; s_barrier; lgkmcnt(0); setprio(1); MFMA;
//               setprio(0); s_barrier}
// Wave-permuted M-rows (wr0: rows 0-63 in p0/p1, 64-95 in p2; wr1: 128-191
// in p0/p1, 96-127 in p2) align 64-row stage granules with read-completion:
//  - p0/p1 targets (slot s^1) last read in tile t-1  -> barrier-complete
//  - p2 targets (slot s) rows {0-63,128-191} + B{0-127} read-complete @ p1
// Counted vmcnt(4) per boundary (4 = previous tile's p2 stages), vmcnt(0)
// only at t=15. Grid 14 x 32 = 448 = 8*56, bijective XCD swizzle.
// ---------------------------------------------------------------------------
__device__ __forceinline__ int sw256(int row, int col) {
  return row * 256 + ((((col >> 3) ^ (row & 31)) << 3) | (col & 7));
}

__global__ __launch_bounds__(512, 2) void bgemm_proj(
    const bf16_t* __restrict__ A, const bf16_t* __restrict__ W,
    const float* __restrict__ ipb, const float* __restrict__ relb,
    bf16_t* __restrict__ qkvb, float* __restrict__ relv2,
    bf16_t* __restrict__ vT) {
  // slot s: A at s*28672 (192x64), B at s*28672+12288 (256x64)
  __shared__ __align__(16) bf16_t smem[57344];   // 112 KB

  const int tid = threadIdx.x;
  const int wave = tid >> 6, lane = tid & 63;
  const int wr = wave >> 2, wc = wave & 3;        // 2 x 4 wave grid
  const int pid = blockIdx.y * 14 + blockIdx.x;   // 448 = 8 * 56
  const int lid = (pid & 7) * 56 + (pid >> 3);
  const int by = lid / 14;
  const int bx = lid - by * 14;
  const int bm = by * 192, bn = bx * 256;
  const int q = lane >> 4, ln = lane & 15;
  const int grow = tid >> 3;                      // 0..63
  const int gcol = ((tid & 7) ^ (grow & 7)) * 8;  // pre-swizzled global col
  const int co[2] = {((q) ^ (ln & 7)) * 8, ((4 + q) ^ (ln & 7)) * 8};

  // acc row mapping (tile-local): mi 0..3 -> wr*128 + mi*16 ;
  //                               mi 4..5 -> 64 + 32*wr + (mi-4)*16
  f32x4 acc[6][4];
#pragma unroll
  for (int mi = 0; mi < 6; ++mi)
#pragma unroll
    for (int ni = 0; ni < 4; ++ni)
#pragma unroll
      for (int r = 0; r < 4; ++r) acc[mi][ni][r] = 0.f;

  auto stA = [&](int kt, int row0) {   // row0 in {0, 64, 128}
    bf16_t* dst = smem + (kt & 1) * 28672 + row0 * 64;
    GLL(&A[(size_t)(bm + row0 + grow) * 1024 + kt * 64 + gcol], &dst[tid * 8]);
  };
  auto stB = [&](int kt, int row0) {   // row0 in {0, 64, 128, 192}
    bf16_t* dst = smem + (kt & 1) * 28672 + 12288 + row0 * 64;
    GLL(&W[(size_t)(bn + row0 + grow) * 1024 + kt * 64 + gcol], &dst[tid * 8]);
  };

  // prologue: tiles 0 and 1 fully staged (14 GLL per thread)
  stA(0, 0); stA(0, 64); stA(0, 128);
  stB(0, 0); stB(0, 64); stB(0, 128); stB(0, 192);
  stA(1, 0); stA(1, 64); stA(1, 128);
  stB(1, 0); stB(1, 64); stB(1, 128); stB(1, 192);
  WVM7();          // tile 0 (oldest 7) resident; tile 1 in flight
  BARX();

#pragma unroll 1
  for (int kt = 0; kt < 16; ++kt) {
    const bf16_t* As = smem + (kt & 1) * 28672;
    const bf16_t* Bs = As + 12288;
    if (kt) {
      if (kt == 15) { WVM0(); } else { WVM4(); }  // tile kt resident
      BARX();
    }
    bf16x8 b0[4], b1[4], a[4];

    // -------- phase 0: mq0 rows x co[0] --------
#pragma unroll
    for (int ni = 0; ni < 4; ++ni)
      b0[ni] = *(const bf16x8*)&Bs[(wc * 64 + ni * 16 + ln) * 64 + co[0]];
#pragma unroll
    for (int j = 0; j < 4; ++j)
      a[j] = *(const bf16x8*)&As[(wr * 128 + j * 16 + ln) * 64 + co[0]];
    if (kt >= 1 && kt <= 14) { stB(kt + 1, 128); stB(kt + 1, 192); }
    BARX(); LGKM0();
    __builtin_amdgcn_s_setprio(1);
#pragma unroll
    for (int j = 0; j < 4; ++j)
#pragma unroll
      for (int ni = 0; ni < 4; ++ni)
        acc[j][ni] = __builtin_amdgcn_mfma_f32_16x16x32_bf16(
            a[j], b0[ni], acc[j][ni], 0, 0, 0);
    __builtin_amdgcn_s_setprio(0);
    BARX();

    // -------- phase 1: mq0 rows x co[1] --------
#pragma unroll
    for (int ni = 0; ni < 4; ++ni)
      b1[ni] = *(const bf16x8*)&Bs[(wc * 64 + ni * 16 + ln) * 64 + co[1]];
#pragma unroll
    for (int j = 0; j < 4; ++j)
      a[j] = *(const bf16x8*)&As[(wr * 128 + j * 16 + ln) * 64 + co[1]];
    if (kt >= 1 && kt <= 14) { stA(kt + 1, 64); }
    BARX(); LGKM0();
    __builtin_amdgcn_s_setprio(1);
#pragma unroll
    for (int j = 0; j < 4; ++j)
#pragma unroll
      for (int ni = 0; ni < 4; ++ni)
        acc[j][ni] = __builtin_amdgcn_mfma_f32_16x16x32_bf16(
            a[j], b1[ni], acc[j][ni], 0, 0, 0);
    __builtin_amdgcn_s_setprio(0);
    BARX();

    // -------- phase 2: mq1 rows x co[0] and co[1] --------
    {
      bf16x8 a2[2], a3[2];
#pragma unroll
      for (int j = 0; j < 2; ++j)
        a2[j] = *(const bf16x8*)&As[(64 + 32 * wr + j * 16 + ln) * 64 + co[0]];
#pragma unroll
      for (int j = 0; j < 2; ++j)
        a3[j] = *(const bf16x8*)&As[(64 + 32 * wr + j * 16 + ln) * 64 + co[1]];
      if (kt <= 13) { stA(kt + 2, 0); stA(kt + 2, 128); stB(kt + 2, 0); stB(kt + 2, 64); }
      BARX(); LGKM0();
      __builtin_amdgcn_s_setprio(1);
#pragma unroll
      for (int j = 0; j < 2; ++j)
#pragma unroll
        for (int ni = 0; ni < 4; ++ni)
          acc[4 + j][ni] = __builtin_amdgcn_mfma_f32_16x16x32_bf16(
              a2[j], b0[ni], acc[4 + j][ni], 0, 0, 0);
#pragma unroll
      for (int j = 0; j < 2; ++j)
#pragma unroll
        for (int ni = 0; ni < 4; ++ni)
          acc[4 + j][ni] = __builtin_amdgcn_mfma_f32_16x16x32_bf16(
              a3[j], b1[ni], acc[4 + j][ni], 0, 0, 0);
      __builtin_amdgcn_s_setprio(0);
      BARX();
    }
  }

  // local row base per acc index (permuted wave->row mapping)
  const int rbase[6] = {wr * 128, wr * 128 + 16, wr * 128 + 32, wr * 128 + 48,
                        64 + 32 * wr, 80 + 32 * wr};

  // ---------------- epilogue (per-block uniform routing) -------------------
  if (bn < 2048) {
    // Q (scaled) and K -> qkvb
    const float sc = (bn < 1024) ? 0.125f : 1.0f;
#pragma unroll
    for (int mi = 0; mi < 6; ++mi) {
#pragma unroll
      for (int ni = 0; ni < 4; ++ni) {
        const int col = bn + wc * 64 + ni * 16 + ln;
        const float bv = ipb[col];
#pragma unroll
        for (int r = 0; r < 4; ++r) {
          const int row = bm + rbase[mi] + q * 4 + r;
          qkvb[(size_t)row * 3072 + col] = (bf16_t)((acc[mi][ni][r] + bv) * sc);
        }
      }
    }
  } else if (bn < 3072) {
    // V: transpose via swizzled 192x256 LDS bounce, write vT[bh][d][token]
    __syncthreads();  // K-loop fully drained; reuse smem as bounce
#pragma unroll
    for (int mi = 0; mi < 6; ++mi) {
#pragma unroll
      for (int ni = 0; ni < 4; ++ni) {
        const int col_l = wc * 64 + ni * 16 + ln;
        const float bv = ipb[bn + col_l];
#pragma unroll
        for (int r = 0; r < 4; ++r) {
          const int row_l = rbase[mi] + q * 4 + r;
          smem[sw256(row_l, col_l)] = (bf16_t)(acc[mi][ni][r] + bv);
        }
      }
    }
    __syncthreads();
    const int h0 = (bn - 2048) >> 6;     // 4 heads per 256-col tile
    const int tb0 = bm >> 2;             // 48 tokens per 192-row tile
#pragma unroll
    for (int e = 0; e < 2; ++e) {
      const int task = e * 512 + tid;    // 1024 tasks: (b, col)
      const int b = task & 3;
      const int c = task >> 2;           // 0..255
      const int h = h0 + (c >> 6);
      const int d = c & 63;
      const size_t base = ((size_t)((b * 16 + h) * 64 + d)) * (size_t)TGT_ + tb0;
#pragma unroll
      for (int k = 0; k < 6; ++k) {
        bf16x8 v8;
#pragma unroll
        for (int i = 0; i < 8; ++i)
          v8[i] = smem[sw256((k * 8 + i) * 4 + b, c)];
        *(bf16x8*)&vT[base + k * 8] = v8;
      }
    }
  } else {
    const int cb = bn - 3072 + wc * 64;
    float4 rb4;
#pragma unroll
    for (int ni = 0; ni < 4; ++ni)
      ((float*)&rb4)[ni] = relb[cb + ni * 16 + ln];
    const int bkbase = cb >> 4;
#pragma unroll
    for (int mi = 0; mi < 6; ++mi) {
#pragma unroll
      for (int r = 0; r < 4; ++r) {
        const int row = bm + rbase[mi] + q * 4 + r;
        float4 v;
        v.x = acc[mi][0][r] + rb4.x;
        v.y = acc[mi][1][r] + rb4.y;
        v.z = acc[mi][2][r] + rb4.z;
        v.w = acc[mi][3][r] + rb4.w;
        *(float4*)&relv2[(size_t)row * 512 + ln * 32 + bkbase] = v;
      }
    }
  }
}

// ---------------------------------------------------------------------------
// Output projection GEMM (fp32 out). Unchanged + XCD swizzle.
// ---------------------------------------------------------------------------
__global__ __launch_bounds__(256, 4) void bgemm_out(
    const bf16_t* __restrict__ A, const bf16_t* __restrict__ W,
    const float* __restrict__ bias, float* __restrict__ C, int N) {
  __shared__ bf16_t As[128 * 64];
  __shared__ bf16_t Bs[128 * 64];

  const int tid = threadIdx.x;
  const int wave = tid >> 6, lane = tid & 63;
  const int wr = wave >> 1, wc = wave & 1;
  const int pid = blockIdx.y * 8 + blockIdx.x;
  const int lid = (pid & 7) * 48 + (pid >> 3);
  const int bm = (lid >> 3) * 128, bn = (lid & 7) * 128;
  const int q = lane >> 4, ln = lane & 15;
  const int grow = tid >> 3;
  const int gcol = ((tid & 7) ^ (grow & 7)) * 8;

  f32x4 acc[4][4];
#pragma unroll
  for (int mi = 0; mi < 4; ++mi)
#pragma unroll
    for (int ni = 0; ni < 4; ++ni)
#pragma unroll
      for (int r = 0; r < 4; ++r) acc[mi][ni][r] = 0.f;

  const int co[2] = {((q) ^ (ln & 7)) * 8, ((4 + q) ^ (ln & 7)) * 8};

  for (int k0 = 0; k0 < 1024; k0 += 64) {
    __syncthreads();
#pragma unroll
    for (int p = 0; p < 4; ++p) {
      GLL(&A[(size_t)(bm + p * 32 + grow) * 1024 + k0 + gcol], &As[p * 2048 + tid * 8]);
      GLL(&W[(size_t)(bn + p * 32 + grow) * 1024 + k0 + gcol], &Bs[p * 2048 + tid * 8]);
    }
    __syncthreads();
#pragma unroll
    for (int t = 0; t < 2; ++t) {
      bf16x8 af[4], bf[4];
#pragma unroll
      for (int mi = 0; mi < 4; ++mi)
        af[mi] = *(const bf16x8*)&As[(wr * 64 + mi * 16 + ln) * 64 + co[t]];
#pragma unroll
      for (int ni = 0; ni < 4; ++ni)
        bf[ni] = *(const bf16x8*)&Bs[(wc * 64 + ni * 16 + ln) * 64 + co[t]];
#pragma unroll
      for (int mi = 0; mi < 4; ++mi)
#pragma unroll
        for (int ni = 0; ni < 4; ++ni)
          acc[mi][ni] = __builtin_amdgcn_mfma_f32_16x16x32_bf16(
              af[mi], bf[ni], acc[mi][ni], 0, 0, 0);
    }
  }

#pragma unroll
  for (int mi = 0; mi < 4; ++mi) {
#pragma unroll
    for (int ni = 0; ni < 4; ++ni) {
      const int col = bn + wc * 64 + ni * 16 + ln;
      const float bv = bias[col];
#pragma unroll
      for (int r = 0; r < 4; ++r) {
        const int row = bm + wr * 64 + mi * 16 + q * 4 + r;
        C[(size_t)row * N + col] = acc[mi][ni][r] + bv;
      }
    }
  }
}

// ---------------------------------------------------------------------------
// MFMA flash attention (unchanged this round).
// ---------------------------------------------------------------------------
__device__ __forceinline__ int bucket_of(int n) {
  if (n < 16) return n;
  const float lf = __log2f((float)n);
  int b = (int)(16.0f + (lf - 4.0f) * 5.3333333f);
  return b > 31 ? 31 : b;
}

__global__ __launch_bounds__(256, 2) void flash_mfma(
    const bf16_t* __restrict__ qkvb, const bf16_t* __restrict__ vT,
    const float* __restrict__ relv2, bf16_t* __restrict__ attn) {
  __shared__ bf16_t Ks[2][64 * 64];
  __shared__ bf16_t Vts[2][64 * 64];
  __shared__ bf16_t Ps[4][16 * 64];
  __shared__ bf16_t biasS[3][64 * 33];

  const int qt = 7 - blockIdx.x, tq0 = qt * 64;
  const int bh = blockIdx.y, b = bh >> 4, h = bh & 15;
  const int tid = threadIdx.x;
  const int wave = tid >> 6, lane = tid & 63;
  const int q = lane >> 4, ln = lane & 15;
  const int m0 = wave * 16;
  const int grow = tid >> 3;
  const int gcol = ((tid & 7) ^ (grow & 7)) * 8;
  const int co[2] = {((q) ^ (ln & 7)) * 8, ((4 + q) ^ (ln & 7)) * 8};

#pragma unroll
  for (int z = 0; z < 3; ++z) {
#pragma unroll
    for (int u = 0; u < 2; ++u) {
      const int c = u * 256 + tid;
      const int row = c >> 3, j4 = (c & 7) * 4;
      const float4 v = *(const float4*)
          &relv2[((size_t)(z * T_ + tq0 + row) * B_ + b) * 512 + h * 32 + j4];
      biasS[z][row * 33 + j4 + 0] = (bf16_t)v.x;
      biasS[z][row * 33 + j4 + 1] = (bf16_t)v.y;
      biasS[z][row * 33 + j4 + 2] = (bf16_t)v.z;
      biasS[z][row * 33 + j4 + 3] = (bf16_t)v.w;
    }
  }

#pragma unroll
  for (int u = 0; u < 2; ++u) {
    const int sr = u * 32 + grow;
    GLL(&qkvb[((size_t)(0 * T_ + tq0 + sr) * B_ + b) * 3072 + h * 64 + gcol],
        &Ks[0][u * 2048 + tid * 8]);
    GLL(&qkvb[((size_t)(1 * T_ + tq0 + sr) * B_ + b) * 3072 + h * 64 + gcol],
        &Vts[0][u * 2048 + tid * 8]);
    GLL(&qkvb[((size_t)(2 * T_ + tq0 + sr) * B_ + b) * 3072 + h * 64 + gcol],
        &Ks[1][u * 2048 + tid * 8]);
  }
  __syncthreads();

  bf16x8 aq[3][2];
  aq[0][0] = *(const bf16x8*)&Ks[0][(m0 + ln) * 64 + co[0]];
  aq[0][1] = *(const bf16x8*)&Ks[0][(m0 + ln) * 64 + co[1]];
  aq[1][0] = *(const bf16x8*)&Vts[0][(m0 + ln) * 64 + co[0]];
  aq[1][1] = *(const bf16x8*)&Vts[0][(m0 + ln) * 64 + co[1]];
  aq[2][0] = *(const bf16x8*)&Ks[1][(m0 + ln) * 64 + co[0]];
  aq[2][1] = *(const bf16x8*)&Ks[1][(m0 + ln) * 64 + co[1]];

  float bv31[3][4], bv0[3][4];
#pragma unroll
  for (int z = 0; z < 3; ++z)
#pragma unroll
    for (int r = 0; r < 4; ++r) {
      const int rloc = m0 + q * 4 + r;
      bv31[z][r] = (float)biasS[z][rloc * 33 + 31];
      bv0[z][r] = (float)biasS[z][rloc * 33];
    }

  f32x4 Od[3][4];
  float lpart[3][4];
#pragma unroll
  for (int z = 0; z < 3; ++z)
#pragma unroll
    for (int r = 0; r < 4; ++r) {
      lpart[z][r] = 0.f;
#pragma unroll
      for (int tc = 0; tc < 4; ++tc) Od[z][tc][r] = 0.f;
    }

  const int ntiles = qt + 3;

  auto stage_tile = [&](int jj, int buf) {
    const int krb = (jj <= qt) ? jj * 64 : ((jj - qt) * T_ + tq0);
#pragma unroll
    for (int u = 0; u < 2; ++u) {
      const int sr = u * 32 + grow;
      GLL(&qkvb[((size_t)(krb + sr) * B_ + b) * 3072 + 1024 + h * 64 + gcol],
          &Ks[buf][u * 2048 + tid * 8]);
      GLL(&vT[((size_t)bh * 64 + sr) * (size_t)TGT_ + krb + gcol],
          &Vts[buf][u * 2048 + tid * 8]);
    }
  };

  __syncthreads();
  stage_tile(0, 0);
  __syncthreads();

  for (int jj = 0; jj < ntiles; ++jj) {
    const int cur = jj & 1;
    if (jj + 1 < ntiles) stage_tile(jj + 1, cur ^ 1);

    const int krb = (jj <= qt) ? jj * 64 : ((jj - qt) * T_ + tq0);

    bf16x8 kf[4][2], vf[4][2];
#pragma unroll
    for (int tc = 0; tc < 4; ++tc) {
      kf[tc][0] = *(const bf16x8*)&Ks[cur][(tc * 16 + ln) * 64 + co[0]];
      kf[tc][1] = *(const bf16x8*)&Ks[cur][(tc * 16 + ln) * 64 + co[1]];
      vf[tc][0] = *(const bf16x8*)&Vts[cur][(tc * 16 + ln) * 64 + co[0]];
      vf[tc][1] = *(const bf16x8*)&Vts[cur][(tc * 16 + ln) * 64 + co[1]];
    }

    if (jj <= qt) {
      const bool far = (jj <= qt - 3);
#pragma unroll
      for (int z = 0; z < 3; ++z) {
        f32x4 acc[4];
#pragma unroll
        for (int tc = 0; tc < 4; ++tc)
#pragma unroll
          for (int r = 0; r < 4; ++r) acc[tc][r] = 0.f;
#pragma unroll
        for (int tc = 0; tc < 4; ++tc) {
          acc[tc] = __builtin_amdgcn_mfma_f32_16x16x32_bf16(aq[z][0], kf[tc][0], acc[tc], 0, 0, 0);
          acc[tc] = __builtin_amdgcn_mfma_f32_16x16x32_bf16(aq[z][1], kf[tc][1], acc[tc], 0, 0, 0);
        }

        if (far) {
#pragma unroll
          for (int r = 0; r < 4; ++r) {
            const float bv = bv31[z][r];
#pragma unroll
            for (int tc = 0; tc < 4; ++tc) {
              const float p = __expf(acc[tc][r] + bv);
              lpart[z][r] += p;
              const int pc = (tc * 2 + (ln >> 3)) ^ ((q * 4 + r) & 7);
              Ps[wave][(q * 4 + r) * 64 + pc * 8 + (ln & 7)] = (bf16_t)p;
            }
          }
        } else {
#pragma unroll
          for (int r = 0; r < 4; ++r) {
            const int rloc = m0 + q * 4 + r;
            const int dbase = tq0 + rloc - krb;
#pragma unroll
            for (int tc = 0; tc < 4; ++tc) {
              const int sl = tc * 16 + ln;
              const int d = dbase - sl;
              const bool valid = (jj < qt) | (d >= 0);
              int n = d < 0 ? 0 : d;
              if (z > 0) n += 1;
              const float bv = (float)biasS[z][rloc * 33 + bucket_of(n)];
              const float p = valid ? __expf(acc[tc][r] + bv) : 0.f;
              lpart[z][r] += p;
              const int pc = (tc * 2 + (ln >> 3)) ^ ((q * 4 + r) & 7);
              Ps[wave][(q * 4 + r) * 64 + pc * 8 + (ln & 7)] = (bf16_t)p;
            }
          }
        }

        bf16x8 ap[2];
        ap[0] = *(const bf16x8*)&Ps[wave][ln * 64 + co[0]];
        ap[1] = *(const bf16x8*)&Ps[wave][ln * 64 + co[1]];
#pragma unroll
        for (int tc = 0; tc < 4; ++tc) {
          Od[z][tc] = __builtin_amdgcn_mfma_f32_16x16x32_bf16(ap[0], vf[tc][0], Od[z][tc], 0, 0, 0);
          Od[z][tc] = __builtin_amdgcn_mfma_f32_16x16x32_bf16(ap[1], vf[tc][1], Od[z][tc], 0, 0, 0);
        }
      }
    } else {
#pragma unroll
      for (int z = 1; z <= 2; ++z) {
        if (jj - qt == z) {
          f32x4 acc[4];
#pragma unroll
          for (int tc = 0; tc < 4; ++tc)
#pragma unroll
            for (int r = 0; r < 4; ++r) acc[tc][r] = 0.f;
#pragma unroll
          for (int tc = 0; tc < 4; ++tc) {
            acc[tc] = __builtin_amdgcn_mfma_f32_16x16x32_bf16(aq[z][0], kf[tc][0], acc[tc], 0, 0, 0);
            acc[tc] = __builtin_amdgcn_mfma_f32_16x16x32_bf16(aq[z][1], kf[tc][1], acc[tc], 0, 0, 0);
          }
#pragma unroll
          for (int r = 0; r < 4; ++r) {
            const int rloc = m0 + q * 4 + r;
            const float bv = bv0[z][r];
#pragma unroll
            for (int tc = 0; tc < 4; ++tc) {
              const int sl = tc * 16 + ln;
              const float p = (sl == rloc) ? __expf(acc[tc][r] + bv) : 0.f;
              lpart[z][r] += p;
              const int pc = (tc * 2 + (ln >> 3)) ^ ((q * 4 + r) & 7);
              Ps[wave][(q * 4 + r) * 64 + pc * 8 + (ln & 7)] = (bf16_t)p;
            }
          }
          bf16x8 ap[2];
          ap[0] = *(const bf16x8*)&Ps[wave][ln * 64 + co[0]];
          ap[1] = *(const bf16x8*)&Ps[wave][ln * 64 + co[1]];
#pragma unroll
          for (int tc = 0; tc < 4; ++tc) {
            Od[z][tc] = __builtin_amdgcn_mfma_f32_16x16x32_bf16(ap[0], vf[tc][0], Od[z][tc], 0, 0, 0);
            Od[z][tc] = __builtin_amdgcn_mfma_f32_16x16x32_bf16(ap[1], vf[tc][1], Od[z][tc], 0, 0, 0);
          }
        }
      }
    }
    __syncthreads();
  }

#pragma unroll
  for (int z = 0; z < 3; ++z) {
#pragma unroll
    for (int r = 0; r < 4; ++r) {
      float l = lpart[z][r];
      l += __shfl_xor(l, 1, 16);
      l += __shfl_xor(l, 2, 16);
      l += __shfl_xor(l, 4, 16);
      l += __shfl_xor(l, 8, 16);
      const float inv = 1.f / l;
      const size_t rowbase =
          ((size_t)(z * T_ + tq0 + m0 + q * 4 + r) * B_ + b) * (size_t)E_ + h * 64;
#pragma unroll
      for (int tc = 0; tc < 4; ++tc)
        attn[rowbase + tc * 16 + ln] = (bf16_t)(Od[z][tc][r] * inv);
    }
  }
}

// ---------------------------------------------------------------------------
extern "C" void kernel_launch(void* const* d_in, const int* in_sizes, int n_in,
                              void* d_out, int out_size, void* d_ws, size_t ws_size,
                              hipStream_t stream) {
  const float* query = (const float*)d_in[0];
  const float* ipw   = (const float*)d_in[1];
  const float* ipb   = (const float*)d_in[2];
  const float* relw  = (const float*)d_in[3];
  const float* relb  = (const float*)d_in[4];
  const float* outw  = (const float*)d_in[5];
  const float* outb  = (const float*)d_in[6];
  float* out = (float*)d_out;

  bf16_t* qkvb  = (bf16_t*)d_ws;                                 // 6144x3072
  float*  relv2 = (float*)(qkvb + (size_t)ROWS_ * 3 * E_);       // 6144x512 f32
  bf16_t* qb    = (bf16_t*)(relv2 + (size_t)ROWS_ * 512);        // 6144x1024
  bf16_t* ipwb  = qb + (size_t)ROWS_ * E_;                       // 3072x1024
  bf16_t* relwb = ipwb + (size_t)(3 * E_) * E_;                  // 512x1024 (adjacent!)
  bf16_t* outwb = relwb + (size_t)512 * E_;                      // 1024x1024
  bf16_t* attnb = outwb + (size_t)E_ * E_;                       // 6144x1024
  bf16_t* vT    = attnb + (size_t)ROWS_ * E_;                    // 64x64x1536

  const dim3 blk(256);

  // 1) conversions
  {
    const int ntot = (ROWS_ * E_ + 3 * E_ * E_ + 512 * E_ + E_ * E_) / 4;
    prep<<<dim3((ntot + 255) / 256), blk, 0, stream>>>(
        query, ipw, relw, outw, qb, ipwb, relwb, outwb);
  }

  // 2) combined QKV + rel projection (BM=192 x BN=256, 8-phase schedule)
  bgemm_proj<<<dim3(3584 / 256, ROWS_ / 192), dim3(512), 0, stream>>>(
      qb, ipwb, ipb, relb, qkvb, relv2, vT);

  // 3) flash attention, all streams merged
  flash_mfma<<<dim3(8, B_ * H_), blk, 0, stream>>>(
      qkvb, vT, relv2, attnb);

  // 4) output projection
  bgemm_out<<<dim3(E_ / 128, ROWS_ / 128), blk, 0, stream>>>(
      attnb, outwb, outb, out, E_);
}

// Round 5
// 239.593 us; speedup vs baseline: 1.0735x; 1.0183x over previous
//
#include <hip/hip_runtime.h>
#include <hip/hip_bf16.h>
#include <math.h>

// Problem constants
constexpr int T_ = 512;
constexpr int B_ = 4;
constexpr int E_ = 1024;
constexpr int H_ = 16;
constexpr int NGRAM_ = 2;
constexpr int TGT_ = (1 + NGRAM_) * T_;   // 1536
constexpr int ROWS_ = TGT_ * B_;          // 6144

typedef __bf16 bf16_t;
typedef __bf16 bf16x8 __attribute__((ext_vector_type(8)));
typedef __bf16 bf16x4 __attribute__((ext_vector_type(4)));
typedef float f32x4 __attribute__((ext_vector_type(4)));

#define GLL(gaddr, laddr)                                                     \
  __builtin_amdgcn_global_load_lds(                                           \
      (const __attribute__((address_space(1))) void*)(gaddr),                 \
      (__attribute__((address_space(3))) void*)(laddr), 16, 0, 0)

// raw barrier / counted waits: asm with memory clobber = compiler fence,
// no compiler-inserted vmcnt(0) drain (unlike __syncthreads()).
#define BARX()  asm volatile("s_barrier" ::: "memory")
#define WVM7()  asm volatile("s_waitcnt vmcnt(7)" ::: "memory")
#define WVM0()  asm volatile("s_waitcnt vmcnt(0)" ::: "memory")

// ---------------------------------------------------------------------------
// prep: all fp32->bf16 conversions, one launch.
// ---------------------------------------------------------------------------
__global__ __launch_bounds__(256) void prep(
    const float* __restrict__ query, const float* __restrict__ ipw,
    const float* __restrict__ relw, const float* __restrict__ outw,
    bf16_t* __restrict__ qb, bf16_t* __restrict__ ipwb,
    bf16_t* __restrict__ relwb, bf16_t* __restrict__ outwb) {
  const int i = blockIdx.x * 256 + threadIdx.x;
  constexpr int N1 = ROWS_ * E_ / 4;
  constexpr int N2 = 3 * E_ * E_ / 4;
  constexpr int N3 = 512 * E_ / 4;
  constexpr int N4 = E_ * E_ / 4;
  const float4* src;
  bf16_t* dst;
  int j = i;
  if (i < N1) { src = (const float4*)query; dst = qb; }
  else if (i < N1 + N2) { src = (const float4*)ipw; dst = ipwb; j = i - N1; }
  else if (i < N1 + N2 + N3) { src = (const float4*)relw; dst = relwb; j = i - N1 - N2; }
  else if (i < N1 + N2 + N3 + N4) { src = (const float4*)outw; dst = outwb; j = i - N1 - N2 - N3; }
  else return;
  const float4 v = src[j];
  bf16x4 o;
  o[0] = (bf16_t)v.x; o[1] = (bf16_t)v.y;
  o[2] = (bf16_t)v.z; o[3] = (bf16_t)v.w;
  ((bf16x4*)dst)[j] = o;
}

// ---------------------------------------------------------------------------
// Combined projection GEMM, BM=192 x BN=256 x BK=64, 512 threads
// (8 waves 2x4, per-wave 96x64 = acc[6][4] f32x4), double-buffered LDS.
// Round-2 schedule (best measured: 67.5us, MfmaUtil 25.5): no intra-tile
// barriers; per K-tile one inter-barrier region with all 20 frag ds_reads
// interleaved 1-subphase-deep with 4x12 MFMA clusters; setprio around
// clusters; counted vmcnt(7) at tile boundaries (vmcnt(0) only at the end).
// Grid 14 x 32 = 448 blocks, bijective XCD swizzle (448 = 8*56).
// ---------------------------------------------------------------------------
__device__ __forceinline__ int sw256(int row, int col) {
  // XOR-swizzled bounce layout for the 192x256 V-tile transpose
  return row * 256 + ((((col >> 3) ^ (row & 31)) << 3) | (col & 7));
}

__global__ __launch_bounds__(512, 2) void bgemm_proj(
    const bf16_t* __restrict__ A, const bf16_t* __restrict__ W,
    const float* __restrict__ ipb, const float* __restrict__ relb,
    bf16_t* __restrict__ qkvb, float* __restrict__ relv2,
    bf16_t* __restrict__ vT) {
  // [As0|As1] 2x192x64, [Bs0|Bs1] 2x256x64  (112 KB total)
  __shared__ bf16_t smem[57344];
  bf16_t* As0 = smem;
  bf16_t* As1 = smem + 12288;
  bf16_t* Bs0 = smem + 24576;
  bf16_t* Bs1 = smem + 24576 + 16384;

  const int tid = threadIdx.x;
  const int wave = tid >> 6, lane = tid & 63;
  const int wr = wave >> 2, wc = wave & 3;       // 2 x 4 wave grid
  // T1: bijective XCD swizzle. 448 blocks = 8 XCDs x 56.
  const int pid = blockIdx.y * 14 + blockIdx.x;
  const int lid = (pid & 7) * 56 + (pid >> 3);
  const int by = lid / 14;
  const int bx = lid - by * 14;
  const int bm = by * 192, bn = bx * 256;
  const int q = lane >> 4, ln = lane & 15;
  const int grow = tid >> 3;                              // 0..63
  const int gcol = ((tid & 7) ^ (grow & 7)) * 8;          // pre-swizzled src
  const int co[2] = {((q) ^ (ln & 7)) * 8, ((4 + q) ^ (ln & 7)) * 8};

  f32x4 acc[6][4];
#pragma unroll
  for (int mi = 0; mi < 6; ++mi)
#pragma unroll
    for (int ni = 0; ni < 4; ++ni)
#pragma unroll
      for (int r = 0; r < 4; ++r) acc[mi][ni][r] = 0.f;

  // stage one K-tile (7 GLL per thread: 3 A-rounds + 4 B-rounds of 64 rows)
  auto stage = [&](int kt, bf16_t* la, bf16_t* lb) {
    const int kc = kt * 64 + gcol;
#pragma unroll
    for (int p = 0; p < 3; ++p)
      GLL(&A[(size_t)(bm + p * 64 + grow) * 1024 + kc], &la[p * 4096 + tid * 8]);
#pragma unroll
    for (int p = 0; p < 4; ++p)
      GLL(&W[(size_t)(bn + p * 64 + grow) * 1024 + kc], &lb[p * 4096 + tid * 8]);
  };

  // One K-tile, barrier-free inside: reads prefetched 1 sub-phase deep,
  // compiler inserts counted lgkmcnt; LDS port streams under the MFMA pipe.
  auto compute_tile = [&](const bf16_t* la, const bf16_t* lb) {
    bf16x8 a0[3], a1[3], b0[4], b1[4];
    // prefetch sub-phase 0 (b0, a0) and sub-phase 1 (a1)
#pragma unroll
    for (int ni = 0; ni < 4; ++ni)
      b0[ni] = *(const bf16x8*)&lb[(wc * 64 + ni * 16 + ln) * 64 + co[0]];
#pragma unroll
    for (int mi = 0; mi < 3; ++mi)
      a0[mi] = *(const bf16x8*)&la[(wr * 96 + mi * 16 + ln) * 64 + co[0]];
#pragma unroll
    for (int mi = 0; mi < 3; ++mi)
      a1[mi] = *(const bf16x8*)&la[(wr * 96 + (3 + mi) * 16 + ln) * 64 + co[0]];
    // s0: acc[0..2] += a0 x b0
    __builtin_amdgcn_s_setprio(1);
#pragma unroll
    for (int mi = 0; mi < 3; ++mi)
#pragma unroll
      for (int ni = 0; ni < 4; ++ni)
        acc[mi][ni] = __builtin_amdgcn_mfma_f32_16x16x32_bf16(
            a0[mi], b0[ni], acc[mi][ni], 0, 0, 0);
    __builtin_amdgcn_s_setprio(0);
    // prefetch sub-phase 2 (b1, a0')
#pragma unroll
    for (int ni = 0; ni < 4; ++ni)
      b1[ni] = *(const bf16x8*)&lb[(wc * 64 + ni * 16 + ln) * 64 + co[1]];
#pragma unroll
    for (int mi = 0; mi < 3; ++mi)
      a0[mi] = *(const bf16x8*)&la[(wr * 96 + mi * 16 + ln) * 64 + co[1]];
    // s1: acc[3..5] += a1 x b0
    __builtin_amdgcn_s_setprio(1);
#pragma unroll
    for (int mi = 0; mi < 3; ++mi)
#pragma unroll
      for (int ni = 0; ni < 4; ++ni)
        acc[3 + mi][ni] = __builtin_amdgcn_mfma_f32_16x16x32_bf16(
            a1[mi], b0[ni], acc[3 + mi][ni], 0, 0, 0);
    __builtin_amdgcn_s_setprio(0);
    // prefetch sub-phase 3 (a1')
#pragma unroll
    for (int mi = 0; mi < 3; ++mi)
      a1[mi] = *(const bf16x8*)&la[(wr * 96 + (3 + mi) * 16 + ln) * 64 + co[1]];
    // s2: acc[0..2] += a0' x b1
    __builtin_amdgcn_s_setprio(1);
#pragma unroll
    for (int mi = 0; mi < 3; ++mi)
#pragma unroll
      for (int ni = 0; ni < 4; ++ni)
        acc[mi][ni] = __builtin_amdgcn_mfma_f32_16x16x32_bf16(
            a0[mi], b1[ni], acc[mi][ni], 0, 0, 0);
    __builtin_amdgcn_s_setprio(0);
    // s3: acc[3..5] += a1' x b1
    __builtin_amdgcn_s_setprio(1);
#pragma unroll
    for (int mi = 0; mi < 3; ++mi)
#pragma unroll
      for (int ni = 0; ni < 4; ++ni)
        acc[3 + mi][ni] = __builtin_amdgcn_mfma_f32_16x16x32_bf16(
            a1[mi], b1[ni], acc[3 + mi][ni], 0, 0, 0);
    __builtin_amdgcn_s_setprio(0);
  };

  // prologue: 2 K-tiles in flight (14 outstanding GLL per thread)
  stage(0, As0, Bs0);
  stage(1, As1, Bs1);

  // main loop. Per tile: WVM(counted) + BAR (residency), barrier-free
  // compute, BAR (reads drained), stage next-next tile into freed buffer.
  for (int kt = 0; kt < 16; kt += 2) {
    WVM7(); BARX();                       // tile kt resident for all waves
    compute_tile(As0, Bs0);
    BARX();                               // all waves done reading buf0
    if (kt + 2 < 16) stage(kt + 2, As0, Bs0);
    if (kt < 14) { WVM7(); } else { WVM0(); }   // tile kt+1 resident
    BARX();
    compute_tile(As1, Bs1);
    BARX();                               // all waves done reading buf1
    if (kt + 3 < 16) stage(kt + 3, As1, Bs1);
  }

  // ---------------- epilogue (per-block uniform routing) -------------------
  if (bn < 2048) {
    // Q (scaled) and K -> qkvb
    const float sc = (bn < 1024) ? 0.125f : 1.0f;
#pragma unroll
    for (int mi = 0; mi < 6; ++mi) {
#pragma unroll
      for (int ni = 0; ni < 4; ++ni) {
        const int col = bn + wc * 64 + ni * 16 + ln;
        const float bv = ipb[col];
#pragma unroll
        for (int r = 0; r < 4; ++r) {
          const int row = bm + wr * 96 + mi * 16 + q * 4 + r;
          qkvb[(size_t)row * 3072 + col] = (bf16_t)((acc[mi][ni][r] + bv) * sc);
        }
      }
    }
  } else if (bn < 3072) {
    // V: transpose in-block via swizzled LDS bounce, write vT[bh][d][token]
    __syncthreads();  // K-loop LDS fully drained; reuse smem as bounce
#pragma unroll
    for (int mi = 0; mi < 6; ++mi) {
#pragma unroll
      for (int ni = 0; ni < 4; ++ni) {
        const int col_l = wc * 64 + ni * 16 + ln;
        const float bv = ipb[bn + col_l];
#pragma unroll
        for (int r = 0; r < 4; ++r) {
          const int row_l = wr * 96 + mi * 16 + q * 4 + r;
          smem[sw256(row_l, col_l)] = (bf16_t)(acc[mi][ni][r] + bv);
        }
      }
    }
    __syncthreads();
    const int h0 = (bn - 2048) >> 6;     // 4 heads per 256-col tile
    const int tb0 = bm >> 2;             // 48 tokens per 192-row tile
#pragma unroll
    for (int e = 0; e < 2; ++e) {
      const int task = e * 512 + tid;    // 1024 tasks: (b, col)
      const int b = task & 3;
      const int c = task >> 2;           // 0..255
      const int h = h0 + (c >> 6);
      const int d = c & 63;
      const size_t base = ((size_t)((b * 16 + h) * 64 + d)) * (size_t)TGT_ + tb0;
#pragma unroll
      for (int k = 0; k < 6; ++k) {
        bf16x8 v8;
#pragma unroll
        for (int i = 0; i < 8; ++i)
          v8[i] = smem[sw256((k * 8 + i) * 4 + b, c)];
        *(bf16x8*)&vT[base + k * 8] = v8;
      }
    }
  } else {
    const int cb = bn - 3072 + wc * 64;
    float4 rb4;
#pragma unroll
    for (int ni = 0; ni < 4; ++ni)
      ((float*)&rb4)[ni] = relb[cb + ni * 16 + ln];
    const int bkbase = cb >> 4;
#pragma unroll
    for (int mi = 0; mi < 6; ++mi) {
#pragma unroll
      for (int r = 0; r < 4; ++r) {
        const int row = bm + wr * 96 + mi * 16 + q * 4 + r;
        float4 v;
        v.x = acc[mi][0][r] + rb4.x;
        v.y = acc[mi][1][r] + rb4.y;
        v.z = acc[mi][2][r] + rb4.z;
        v.w = acc[mi][3][r] + rb4.w;
        *(float4*)&relv2[(size_t)row * 512 + ln * 32 + bkbase] = v;
      }
    }
  }
}

// ---------------------------------------------------------------------------
// Output projection GEMM (fp32 out). Unchanged + XCD swizzle.
// ---------------------------------------------------------------------------
__global__ __launch_bounds__(256, 4) void bgemm_out(
    const bf16_t* __restrict__ A, const bf16_t* __restrict__ W,
    const float* __restrict__ bias, float* __restrict__ C, int N) {
  __shared__ bf16_t As[128 * 64];
  __shared__ bf16_t Bs[128 * 64];

  const int tid = threadIdx.x;
  const int wave = tid >> 6, lane = tid & 63;
  const int wr = wave >> 1, wc = wave & 1;
  const int pid = blockIdx.y * 8 + blockIdx.x;
  const int lid = (pid & 7) * 48 + (pid >> 3);
  const int bm = (lid >> 3) * 128, bn = (lid & 7) * 128;
  const int q = lane >> 4, ln = lane & 15;
  const int grow = tid >> 3;
  const int gcol = ((tid & 7) ^ (grow & 7)) * 8;

  f32x4 acc[4][4];
#pragma unroll
  for (int mi = 0; mi < 4; ++mi)
#pragma unroll
    for (int ni = 0; ni < 4; ++ni)
#pragma unroll
      for (int r = 0; r < 4; ++r) acc[mi][ni][r] = 0.f;

  const int co[2] = {((q) ^ (ln & 7)) * 8, ((4 + q) ^ (ln & 7)) * 8};

  for (int k0 = 0; k0 < 1024; k0 += 64) {
    __syncthreads();
#pragma unroll
    for (int p = 0; p < 4; ++p) {
      GLL(&A[(size_t)(bm + p * 32 + grow) * 1024 + k0 + gcol], &As[p * 2048 + tid * 8]);
      GLL(&W[(size_t)(bn + p * 32 + grow) * 1024 + k0 + gcol], &Bs[p * 2048 + tid * 8]);
    }
    __syncthreads();
#pragma unroll
    for (int t = 0; t < 2; ++t) {
      bf16x8 af[4], bf[4];
#pragma unroll
      for (int mi = 0; mi < 4; ++mi)
        af[mi] = *(const bf16x8*)&As[(wr * 64 + mi * 16 + ln) * 64 + co[t]];
#pragma unroll
      for (int ni = 0; ni < 4; ++ni)
        bf[ni] = *(const bf16x8*)&Bs[(wc * 64 + ni * 16 + ln) * 64 + co[t]];
#pragma unroll
      for (int mi = 0; mi < 4; ++mi)
#pragma unroll
        for (int ni = 0; ni < 4; ++ni)
          acc[mi][ni] = __builtin_amdgcn_mfma_f32_16x16x32_bf16(
              af[mi], bf[ni], acc[mi][ni], 0, 0, 0);
    }
  }

#pragma unroll
  for (int mi = 0; mi < 4; ++mi) {
#pragma unroll
    for (int ni = 0; ni < 4; ++ni) {
      const int col = bn + wc * 64 + ni * 16 + ln;
      const float bv = bias[col];
#pragma unroll
      for (int r = 0; r < 4; ++r) {
        const int row = bm + wr * 64 + mi * 16 + q * 4 + r;
        C[(size_t)row * N + col] = acc[mi][ni][r] + bv;
      }
    }
  }
}

// ---------------------------------------------------------------------------
// MFMA flash attention. Round-5 change: XCD-balanced block mapping.
// Old grid (8,64): linear id % 8 == qt-index -> XCD0 got ONLY qt=7 blocks
// (10 tiles) and XCD7 only qt=0 (3 tiles) -> makespan set by the all-heavy
// XCD. New grid (64,8): bh is the fast dim (64%8==0 -> uniform bh per XCD)
// and qt is rotated by bh>>3 so every consecutive 8-block group spans all
// qt values -> per-XCD and per-CU work ~constant. Math unchanged.
// ---------------------------------------------------------------------------
__device__ __forceinline__ int bucket_of(int n) {
  if (n < 16) return n;
  const float lf = __log2f((float)n);
  int b = (int)(16.0f + (lf - 4.0f) * 5.3333333f);
  return b > 31 ? 31 : b;
}

__global__ __launch_bounds__(256, 2) void flash_mfma(
    const bf16_t* __restrict__ qkvb, const bf16_t* __restrict__ vT,
    const float* __restrict__ relv2, bf16_t* __restrict__ attn) {
  __shared__ bf16_t Ks[2][64 * 64];
  __shared__ bf16_t Vts[2][64 * 64];
  __shared__ bf16_t Ps[4][16 * 64];
  __shared__ bf16_t biasS[3][64 * 33];

  const int bh = blockIdx.x;               // fast dim: 64 values, uniform/XCD
  const int qt = 7 - ((blockIdx.y + (bh >> 3)) & 7);   // rotated balance
  const int tq0 = qt * 64;
  const int b = bh >> 4, h = bh & 15;
  const int tid = threadIdx.x;
  const int wave = tid >> 6, lane = tid & 63;
  const int q = lane >> 4, ln = lane & 15;
  const int m0 = wave * 16;
  const int grow = tid >> 3;
  const int gcol = ((tid & 7) ^ (grow & 7)) * 8;
  const int co[2] = {((q) ^ (ln & 7)) * 8, ((4 + q) ^ (ln & 7)) * 8};

#pragma unroll
  for (int z = 0; z < 3; ++z) {
#pragma unroll
    for (int u = 0; u < 2; ++u) {
      const int c = u * 256 + tid;
      const int row = c >> 3, j4 = (c & 7) * 4;
      const float4 v = *(const float4*)
          &relv2[((size_t)(z * T_ + tq0 + row) * B_ + b) * 512 + h * 32 + j4];
      biasS[z][row * 33 + j4 + 0] = (bf16_t)v.x;
      biasS[z][row * 33 + j4 + 1] = (bf16_t)v.y;
      biasS[z][row * 33 + j4 + 2] = (bf16_t)v.z;
      biasS[z][row * 33 + j4 + 3] = (bf16_t)v.w;
    }
  }

#pragma unroll
  for (int u = 0; u < 2; ++u) {
    const int sr = u * 32 + grow;
    GLL(&qkvb[((size_t)(0 * T_ + tq0 + sr) * B_ + b) * 3072 + h * 64 + gcol],
        &Ks[0][u * 2048 + tid * 8]);
    GLL(&qkvb[((size_t)(1 * T_ + tq0 + sr) * B_ + b) * 3072 + h * 64 + gcol],
        &Vts[0][u * 2048 + tid * 8]);
    GLL(&qkvb[((size_t)(2 * T_ + tq0 + sr) * B_ + b) * 3072 + h * 64 + gcol],
        &Ks[1][u * 2048 + tid * 8]);
  }
  __syncthreads();

  bf16x8 aq[3][2];
  aq[0][0] = *(const bf16x8*)&Ks[0][(m0 + ln) * 64 + co[0]];
  aq[0][1] = *(const bf16x8*)&Ks[0][(m0 + ln) * 64 + co[1]];
  aq[1][0] = *(const bf16x8*)&Vts[0][(m0 + ln) * 64 + co[0]];
  aq[1][1] = *(const bf16x8*)&Vts[0][(m0 + ln) * 64 + co[1]];
  aq[2][0] = *(const bf16x8*)&Ks[1][(m0 + ln) * 64 + co[0]];
  aq[2][1] = *(const bf16x8*)&Ks[1][(m0 + ln) * 64 + co[1]];

  float bv31[3][4], bv0[3][4];
#pragma unroll
  for (int z = 0; z < 3; ++z)
#pragma unroll
    for (int r = 0; r < 4; ++r) {
      const int rloc = m0 + q * 4 + r;
      bv31[z][r] = (float)biasS[z][rloc * 33 + 31];
      bv0[z][r] = (float)biasS[z][rloc * 33];
    }

  f32x4 Od[3][4];
  float lpart[3][4];
#pragma unroll
  for (int z = 0; z < 3; ++z)
#pragma unroll
    for (int r = 0; r < 4; ++r) {
      lpart[z][r] = 0.f;
#pragma unroll
      for (int tc = 0; tc < 4; ++tc) Od[z][tc][r] = 0.f;
    }

  const int ntiles = qt + 3;

  auto stage_tile = [&](int jj, int buf) {
    const int krb = (jj <= qt) ? jj * 64 : ((jj - qt) * T_ + tq0);
#pragma unroll
    for (int u = 0; u < 2; ++u) {
      const int sr = u * 32 + grow;
      GLL(&qkvb[((size_t)(krb + sr) * B_ + b) * 3072 + 1024 + h * 64 + gcol],
          &Ks[buf][u * 2048 + tid * 8]);
      GLL(&vT[((size_t)bh * 64 + sr) * (size_t)TGT_ + krb + gcol],
          &Vts[buf][u * 2048 + tid * 8]);
    }
  };

  __syncthreads();
  stage_tile(0, 0);
  __syncthreads();

  for (int jj = 0; jj < ntiles; ++jj) {
    const int cur = jj & 1;
    if (jj + 1 < ntiles) stage_tile(jj + 1, cur ^ 1);

    const int krb = (jj <= qt) ? jj * 64 : ((jj - qt) * T_ + tq0);

    bf16x8 kf[4][2], vf[4][2];
#pragma unroll
    for (int tc = 0; tc < 4; ++tc) {
      kf[tc][0] = *(const bf16x8*)&Ks[cur][(tc * 16 + ln) * 64 + co[0]];
      kf[tc][1] = *(const bf16x8*)&Ks[cur][(tc * 16 + ln) * 64 + co[1]];
      vf[tc][0] = *(const bf16x8*)&Vts[cur][(tc * 16 + ln) * 64 + co[0]];
      vf[tc][1] = *(const bf16x8*)&Vts[cur][(tc * 16 + ln) * 64 + co[1]];
    }

    if (jj <= qt) {
      const bool far = (jj <= qt - 3);
#pragma unroll
      for (int z = 0; z < 3; ++z) {
        f32x4 acc[4];
#pragma unroll
        for (int tc = 0; tc < 4; ++tc)
#pragma unroll
          for (int r = 0; r < 4; ++r) acc[tc][r] = 0.f;
#pragma unroll
        for (int tc = 0; tc < 4; ++tc) {
          acc[tc] = __builtin_amdgcn_mfma_f32_16x16x32_bf16(aq[z][0], kf[tc][0], acc[tc], 0, 0, 0);
          acc[tc] = __builtin_amdgcn_mfma_f32_16x16x32_bf16(aq[z][1], kf[tc][1], acc[tc], 0, 0, 0);
        }

        if (far) {
#pragma unroll
          for (int r = 0; r < 4; ++r) {
            const float bv = bv31[z][r];
#pragma unroll
            for (int tc = 0; tc < 4; ++tc) {
              const float p = __expf(acc[tc][r] + bv);
              lpart[z][r] += p;
              const int pc = (tc * 2 + (ln >> 3)) ^ ((q * 4 + r) & 7);
              Ps[wave][(q * 4 + r) * 64 + pc * 8 + (ln & 7)] = (bf16_t)p;
            }
          }
        } else {
#pragma unroll
          for (int r = 0; r < 4; ++r) {
            const int rloc = m0 + q * 4 + r;
            const int dbase = tq0 + rloc - krb;
#pragma unroll
            for (int tc = 0; tc < 4; ++tc) {
              const int sl = tc * 16 + ln;
              const int d = dbase - sl;
              const bool valid = (jj < qt) | (d >= 0);
              int n = d < 0 ? 0 : d;
              if (z > 0) n += 1;
              const float bv = (float)biasS[z][rloc * 33 + bucket_of(n)];
              const float p = valid ? __expf(acc[tc][r] + bv) : 0.f;
              lpart[z][r] += p;
              const int pc = (tc * 2 + (ln >> 3)) ^ ((q * 4 + r) & 7);
              Ps[wave][(q * 4 + r) * 64 + pc * 8 + (ln & 7)] = (bf16_t)p;
            }
          }
        }

        bf16x8 ap[2];
        ap[0] = *(const bf16x8*)&Ps[wave][ln * 64 + co[0]];
        ap[1] = *(const bf16x8*)&Ps[wave][ln * 64 + co[1]];
#pragma unroll
        for (int tc = 0; tc < 4; ++tc) {
          Od[z][tc] = __builtin_amdgcn_mfma_f32_16x16x32_bf16(ap[0], vf[tc][0], Od[z][tc], 0, 0, 0);
          Od[z][tc] = __builtin_amdgcn_mfma_f32_16x16x32_bf16(ap[1], vf[tc][1], Od[z][tc], 0, 0, 0);
        }
      }
    } else {
#pragma unroll
      for (int z = 1; z <= 2; ++z) {
        if (jj - qt == z) {
          f32x4 acc[4];
#pragma unroll
          for (int tc = 0; tc < 4; ++tc)
#pragma unroll
            for (int r = 0; r < 4; ++r) acc[tc][r] = 0.f;
#pragma unroll
          for (int tc = 0; tc < 4; ++tc) {
            acc[tc] = __builtin_amdgcn_mfma_f32_16x16x32_bf16(aq[z][0], kf[tc][0], acc[tc], 0, 0, 0);
            acc[tc] = __builtin_amdgcn_mfma_f32_16x16x32_bf16(aq[z][1], kf[tc][1], acc[tc], 0, 0, 0);
          }
#pragma unroll
          for (int r = 0; r < 4; ++r) {
            const int rloc = m0 + q * 4 + r;
            const float bv = bv0[z][r];
#pragma unroll
            for (int tc = 0; tc < 4; ++tc) {
              const int sl = tc * 16 + ln;
              const float p = (sl == rloc) ? __expf(acc[tc][r] + bv) : 0.f;
              lpart[z][r] += p;
              const int pc = (tc * 2 + (ln >> 3)) ^ ((q * 4 + r) & 7);
              Ps[wave][(q * 4 + r) * 64 + pc * 8 + (ln & 7)] = (bf16_t)p;
            }
          }
          bf16x8 ap[2];
          ap[0] = *(const bf16x8*)&Ps[wave][ln * 64 + co[0]];
          ap[1] = *(const bf16x8*)&Ps[wave][ln * 64 + co[1]];
#pragma unroll
          for (int tc = 0; tc < 4; ++tc) {
            Od[z][tc] = __builtin_amdgcn_mfma_f32_16x16x32_bf16(ap[0], vf[tc][0], Od[z][tc], 0, 0, 0);
            Od[z][tc] = __builtin_amdgcn_mfma_f32_16x16x32_bf16(ap[1], vf[tc][1], Od[z][tc], 0, 0, 0);
          }
        }
      }
    }
    __syncthreads();
  }

#pragma unroll
  for (int z = 0; z < 3; ++z) {
#pragma unroll
    for (int r = 0; r < 4; ++r) {
      float l = lpart[z][r];
      l += __shfl_xor(l, 1, 16);
      l += __shfl_xor(l, 2, 16);
      l += __shfl_xor(l, 4, 16);
      l += __shfl_xor(l, 8, 16);
      const float inv = 1.f / l;
      const size_t rowbase =
          ((size_t)(z * T_ + tq0 + m0 + q * 4 + r) * B_ + b) * (size_t)E_ + h * 64;
#pragma unroll
      for (int tc = 0; tc < 4; ++tc)
        attn[rowbase + tc * 16 + ln] = (bf16_t)(Od[z][tc][r] * inv);
    }
  }
}

// ---------------------------------------------------------------------------
extern "C" void kernel_launch(void* const* d_in, const int* in_sizes, int n_in,
                              void* d_out, int out_size, void* d_ws, size_t ws_size,
                              hipStream_t stream) {
  const float* query = (const float*)d_in[0];
  const float* ipw   = (const float*)d_in[1];
  const float* ipb   = (const float*)d_in[2];
  const float* relw  = (const float*)d_in[3];
  const float* relb  = (const float*)d_in[4];
  const float* outw  = (const float*)d_in[5];
  const float* outb  = (const float*)d_in[6];
  float* out = (float*)d_out;

  bf16_t* qkvb  = (bf16_t*)d_ws;                                 // 6144x3072
  float*  relv2 = (float*)(qkvb + (size_t)ROWS_ * 3 * E_);       // 6144x512 f32
  bf16_t* qb    = (bf16_t*)(relv2 + (size_t)ROWS_ * 512);        // 6144x1024
  bf16_t* ipwb  = qb + (size_t)ROWS_ * E_;                       // 3072x1024
  bf16_t* relwb = ipwb + (size_t)(3 * E_) * E_;                  // 512x1024 (adjacent!)
  bf16_t* outwb = relwb + (size_t)512 * E_;                      // 1024x1024
  bf16_t* attnb = outwb + (size_t)E_ * E_;                       // 6144x1024
  bf16_t* vT    = attnb + (size_t)ROWS_ * E_;                    // 64x64x1536

  const dim3 blk(256);

  // 1) conversions
  {
    const int ntot = (ROWS_ * E_ + 3 * E_ * E_ + 512 * E_ + E_ * E_) / 4;
    prep<<<dim3((ntot + 255) / 256), blk, 0, stream>>>(
        query, ipw, relw, outw, qb, ipwb, relwb, outwb);
  }

  // 2) combined QKV + rel projection (BM=192 x BN=256, 512 threads/block)
  bgemm_proj<<<dim3(3584 / 256, ROWS_ / 192), dim3(512), 0, stream>>>(
      qb, ipwb, ipb, relb, qkvb, relv2, vT);

  // 3) flash attention, XCD-balanced grid (bh fast, qt rotated)
  flash_mfma<<<dim3(64, 8), blk, 0, stream>>>(
      qkvb, vT, relv2, attnb);

  // 4) output projection
  bgemm_out<<<dim3(E_ / 128, ROWS_ / 128), blk, 0, stream>>>(
      attnb, outwb, outb, out, E_);
}